// Round 7
// baseline (174.554 us; speedup 1.0000x reference)
//
#include <hip/hip_runtime.h>

// ActorCriticLoss fused kernel, 4 rows per wave for latency hiding.
//   out[0 .. B*T)        = sigmoid(logits)
//   out[B*T .. B*T+B*63) = lambda returns (reverse affine scan over T)
//
// Lane = timestep t, wave handles ROWS consecutive rows. All 4*ROWS input
// loads issue before any dependent use (hides HBM latency); the ROWS
// independent 6-step Hillis-Steele affine suffix scans are interleaved per
// step (hides ds_bpermute latency).
//   a_t = GAMMA*LAMDA*c_t
//   b_t = r_t + GAMMA*(1-LAMDA)*c_t*v_{t+1}
//   ret_t = (f_t o ... o f_62)(v_63);  lane 63 = identity map.

constexpr float GAMMA = 0.997f;
constexpr float LAMDA = 0.95f;
constexpr int T = 64;
constexpr int ROWS = 4;   // rows per wave

__global__ __launch_bounds__(256) void fused_k(const float* __restrict__ logits,
                                               const float* __restrict__ rew,
                                               const float* __restrict__ con,
                                               const float* __restrict__ val,
                                               float* __restrict__ out_sig,
                                               float* __restrict__ out_ret,
                                               int B) {
  const int gid  = blockIdx.x * blockDim.x + threadIdx.x;
  const int wid  = gid >> 6;
  const int lane = gid & 63;
  const int row0 = wid * ROWS;
  if (row0 >= B) return;

  // ---- issue ALL input loads first (16 outstanding vector loads) ----
  float x[ROWS], r[ROWS], c[ROWS], v[ROWS];
#pragma unroll
  for (int i = 0; i < ROWS; ++i) {
    const size_t idx = (size_t)(row0 + i) * T + lane;
    x[i] = logits[idx];
    r[i] = rew[idx];
    c[i] = con[idx];
    v[i] = val[idx];
  }

  // ---- sigmoid (coalesced 256B store per row) ----
#pragma unroll
  for (int i = 0; i < ROWS; ++i) {
    const size_t idx = (size_t)(row0 + i) * T + lane;
    out_sig[idx] = 1.0f / (1.0f + __expf(-x[i]));
  }

  // ---- lambda returns: ROWS independent wave-parallel affine scans ----
  const int srcn = (lane < 63) ? lane + 1 : 63;
  float A[ROWS], Bc[ROWS];
#pragma unroll
  for (int i = 0; i < ROWS; ++i) {
    const float vnext = __shfl(v[i], srcn);          // v_{t+1}
    if (lane == 63) { A[i] = 1.0f; Bc[i] = 0.0f; }   // identity boundary
    else {
      A[i]  = (GAMMA * LAMDA) * c[i];
      Bc[i] = fmaf((GAMMA * (1.0f - LAMDA)) * c[i], vnext, r[i]);
    }
  }

  // Inclusive suffix scan; interleave rows within each step for LDS-pipe ILP.
#pragma unroll
  for (int d = 1; d < 64; d <<= 1) {
    int src = lane + d;
    if (src > 63) src = 63;        // lane 63 stays identity -> clamp exact
#pragma unroll
    for (int i = 0; i < ROWS; ++i) {
      const float Ain = __shfl(A[i], src);
      const float Bin = __shfl(Bc[i], src);
      Bc[i] = fmaf(A[i], Bin, Bc[i]);   // self o src
      A[i]  = A[i] * Ain;
    }
  }

#pragma unroll
  for (int i = 0; i < ROWS; ++i) {
    // bootstrap = values[:, -1]; uniform lane -> scalar readlane, no bpermute
    const float v63 = __uint_as_float(__builtin_amdgcn_readlane(__float_as_uint(v[i]), 63));
    const float ret = fmaf(A[i], v63, Bc[i]);
    if (lane < 63) out_ret[(size_t)(row0 + i) * 63 + lane] = ret;
  }
}

extern "C" void kernel_launch(void* const* d_in, const int* in_sizes, int n_in,
                              void* d_out, int out_size, void* d_ws, size_t ws_size,
                              hipStream_t stream) {
  const float* logits = (const float*)d_in[0];
  const float* rew    = (const float*)d_in[1];
  const float* con    = (const float*)d_in[2];
  const float* val    = (const float*)d_in[3];
  float* out = (float*)d_out;

  const int BT = in_sizes[0];   // B*T
  const int B  = BT / T;

  float* out_sig = out;                  // B*T floats
  float* out_ret = out + (size_t)BT;     // B*63 floats

  // ROWS rows per wave, 4 waves per block -> 16 rows per block
  const int rows_per_block = ROWS * 4;
  const int blocks = (B + rows_per_block - 1) / rows_per_block;
  fused_k<<<blocks, 256, 0, stream>>>(logits, rew, con, val, out_sig, out_ret, B);
}